// Round 5
// baseline (76.714 us; speedup 1.0000x reference)
//
#include <hip/hip_runtime.h>
#include <stdint.h>

#define BLOCK 512
#define CAP 512           // candidate buffer; <= BLOCK
#define TBL0 16           // int offset of label tables in ws
#define TBLW 2408         // ints per shifted table (4 tables)
#define WS_ROUT 10240     // int offset of per-row partials (float)
static constexpr int LBL = 8;

#define A1 0.1f
#define A2 5.0f
#define A3 10.0f

__device__ __forceinline__ unsigned f2key(float f) {
  unsigned u = __float_as_uint(f);
  return (u & 0x80000000u) ? ~u : (u | 0x80000000u);
}
__device__ __forceinline__ float key2f(unsigned k) {
  unsigned u = (k & 0x80000000u) ? (k & 0x7FFFFFFFu) : ~k;
  return __uint_as_float(u);
}
__device__ __forceinline__ float sigm(float v) { return 1.0f / (1.0f + __expf(-v)); }

// ws[1]=isByteLayout. Detect: a 0x01 byte at index % 4 != 0 can only occur
// if wl was marshalled as 1-byte bools (int32 1 = bytes [1,0,0,0]).
__global__ void detect_kernel(const unsigned char* __restrict__ wl, int total,
                              int* __restrict__ ws) {
  int i = blockIdx.x * 256 + threadIdx.x;
  if (i < total && (i & 3) != 0 && wl[i] == 1) atomicOr(&ws[1], 1);
}

// Label tables: T_s byte (c - s) = label of column c (0..7) or 0xFF.
// Tables pre-memset to 0xFF; only whitelisted columns written here.
__global__ void build_lmap(const unsigned char* __restrict__ wl, int C,
                           int* __restrict__ ws) {
  int c = blockIdx.x * 256 + threadIdx.x;
  if (c >= C) return;
  int isByte = ws[1];
  unsigned lab = 255u;
  if (isByte) {
    for (int l = 0; l < LBL; ++l)
      if (wl[(long long)l * C + c]) lab = (unsigned)l;
  } else {
    const int* w = (const int*)wl;
    for (int l = 0; l < LBL; ++l)
      if (w[(long long)l * C + c]) lab = (unsigned)l;
  }
  if (lab < (unsigned)LBL) {
#pragma unroll
    for (int s2 = 0; s2 < 4; ++s2)
      if (c >= s2) {
        unsigned char* tb = (unsigned char*)(ws + TBL0 + s2 * TBLW);
        tb[c - s2] = (unsigned char)lab;
      }
  }
}

__global__ __launch_bounds__(BLOCK, 8) void rank_kernel(
    const float* __restrict__ x, const float* __restrict__ y,
    const int* __restrict__ ws, float* __restrict__ rout, int C) {
  __shared__ unsigned hist[2048];  // fallback only
  __shared__ unsigned buf[CAP];
  __shared__ float wtop2[BLOCK / 64];
  __shared__ unsigned wtot[BLOCK / 64];
  __shared__ unsigned lmaxk[LBL];
  __shared__ float smL[LBL];
  __shared__ unsigned gtbits, bufcnt, s_seld, s_selk, s_selc, s_key;

  int tid = threadIdx.x;
  int row = blockIdx.x;
  long long base = (long long)row * C;
  const float* __restrict__ xr = x + base;
  const float* __restrict__ yr = y + base;

  int s = (int)((4 - (base & 3)) & 3);  // elems to reach 16B alignment
  int nv = (C - s) >> 2;
  int tail0 = s + 4 * nv;
  int nrem = C - 4 * nv;  // = s + tail, <= 6

  const unsigned* Ts = (const unsigned*)(ws + TBL0 + s * TBLW);
  const unsigned char* Tb = (const unsigned char*)Ts;          // byte idx c-s
  const unsigned char* T0b = (const unsigned char*)(ws + TBL0);  // byte idx c

  // ---- issue stream + label-table loads first (fill the memory pipe) ----
  const float4* __restrict__ xv4 = (const float4*)(xr + s);
  const float4* __restrict__ yv4 = (const float4*)(yr + s);
  float4 f[5];
  bool hv[5];
  unsigned lw[5];
#pragma unroll
  for (int t = 0; t < 5; ++t) {
    int i = tid + t * BLOCK;
    hv[t] = (i < nv);
    f[t] = hv[t] ? xv4[i] : make_float4(-INFINITY, -INFINITY, -INFINITY, -INFINITY);
    lw[t] = hv[t] ? Ts[i] : 0xFFFFFFFFu;
  }
  float tailv = -INFINITY;
  bool havet = false;
  unsigned tlab = 255u;
  int tc = 0;
  if (tid < nrem) {
    tc = (tid < s) ? tid : tail0 + (tid - s);
    tailv = xr[tc];
    havet = true;
    tlab = (tid < s) ? (unsigned)T0b[tc] : (unsigned)Tb[tc - s];
  }
  if (tid < LBL) smL[tid] = xr[tid];  // snapshot x[row, 0..7] for epilogue

  // ---- init LDS, then barrier BEFORE any LDS atomics (race fix) ----
  if (tid < LBL) lmaxk[tid] = 0u;
  if (tid == 0) { gtbits = 0u; bufcnt = 0u; }
  __syncthreads();

  // ---- inline whitelist: per-label max from registers, gt bits from y ----
#pragma unroll
  for (int t = 0; t < 5; ++t) {
    if (lw[t] != 0xFFFFFFFFu) {  // ~7% of words hit
      float4 yv = yv4[tid + t * BLOCK];
      unsigned w2 = lw[t];
      float fe[4] = {f[t].x, f[t].y, f[t].z, f[t].w};
      float ye[4] = {yv.x, yv.y, yv.z, yv.w};
#pragma unroll
      for (int e = 0; e < 4; ++e) {
        unsigned lab = (w2 >> (8 * e)) & 255u;
        if (lab < (unsigned)LBL) {
          atomicMax(&lmaxk[lab], f2key(fe[e]));
          if (ye[e] != 0.0f) atomicOr(&gtbits, 1u << lab);
        }
      }
    }
  }
  if (havet && tlab < (unsigned)LBL) {
    atomicMax(&lmaxk[tlab], f2key(tailv));
    if (yr[tc] != 0.0f) atomicOr(&gtbits, 1u << tlab);
  }

  // ---- per-thread max ----
  float tmax = tailv;
#pragma unroll
  for (int t = 0; t < 5; ++t)
    tmax = fmaxf(tmax, fmaxf(fmaxf(f[t].x, f[t].y), fmaxf(f[t].z, f[t].w)));

  // ---- wave top-2 of thread-maxes; p = min over waves of wave-2nd ----
  float a1 = tmax, a2 = -INFINITY;
#pragma unroll
  for (int st = 1; st < 64; st <<= 1) {
    float b1 = __shfl_xor(a1, st, 64);
    float b2 = __shfl_xor(a2, st, 64);
    float m = fminf(a1, b1);
    float o = (a1 >= b1) ? a2 : b2;
    a1 = fmaxf(a1, b1);
    a2 = fmaxf(m, o);
  }
  int w = tid >> 6;
  if ((tid & 63) == 0) wtop2[w] = a2;
  __syncthreads();
  float p = wtop2[0];
#pragma unroll
  for (int i = 1; i < BLOCK / 64; ++i) p = fminf(p, wtop2[i]);
  // >= 2 elements per wave >= p  =>  >= 16 candidates; 16th largest among them.

  // ---- collect candidates >= p ----
#pragma unroll
  for (int t = 0; t < 5; ++t) {
    if (f[t].x >= p) { unsigned q = atomicAdd(&bufcnt, 1u); if (q < CAP) buf[q] = f2key(f[t].x); }
    if (f[t].y >= p) { unsigned q = atomicAdd(&bufcnt, 1u); if (q < CAP) buf[q] = f2key(f[t].y); }
    if (f[t].z >= p) { unsigned q = atomicAdd(&bufcnt, 1u); if (q < CAP) buf[q] = f2key(f[t].z); }
    if (f[t].w >= p) { unsigned q = atomicAdd(&bufcnt, 1u); if (q < CAP) buf[q] = f2key(f[t].w); }
  }
  if (havet && tailv >= p) { unsigned q = atomicAdd(&bufcnt, 1u); if (q < CAP) buf[q] = f2key(tailv); }
  __syncthreads();

  unsigned selkey = 0u;
  int bc = (int)bufcnt;
  if (bc >= 16 && bc <= CAP) {
    // ---- exact rank-16 among candidates; wave 0 only (tie-correct) ----
    if (tid < 64) {
      for (int i = tid; i < bc; i += 64) {
        unsigned mk = buf[i];
        int g = 0, e2 = 0;
        for (int j = 0; j < bc; ++j) {
          unsigned bk = buf[j];  // LDS broadcast
          g += (bk > mk);
          e2 += (bk == mk);
        }
        if (g < 16 && 16 <= g + e2) s_key = mk;  // ties write same value
      }
    }
    __syncthreads();
    selkey = s_key;
  } else {
    // ---- fallback (block-uniform, rare): 3-level histogram select ----
    unsigned prefix = 0, pmask = 0;
    int k = 16;
    bool done = false;
    const int SHa[3] = {21, 10, 0};
    const int WIDa[3] = {11, 11, 10};
    for (int lev = 0; lev < 3 && !done; ++lev) {
      int shift = SHa[lev];
      int nb = 1 << WIDa[lev];
      unsigned bmask = (unsigned)nb - 1u;
      for (int i = tid; i < nb; i += BLOCK) hist[i] = 0;
      if (tid == 0) bufcnt = 0;
      __syncthreads();
#pragma unroll
      for (int t = 0; t < 5; ++t)
        if (hv[t]) {
          unsigned kk[4] = {f2key(f[t].x), f2key(f[t].y), f2key(f[t].z), f2key(f[t].w)};
#pragma unroll
          for (int e = 0; e < 4; ++e)
            if ((kk[e] & pmask) == prefix) atomicAdd(&hist[(kk[e] >> shift) & bmask], 1u);
        }
      if (havet) {
        unsigned tk = f2key(tailv);
        if ((tk & pmask) == prefix) atomicAdd(&hist[(tk >> shift) & bmask], 1u);
      }
      __syncthreads();
      int bpt = nb / BLOCK;
      int b0 = tid * bpt;
      unsigned cs = 0;
      for (int b = 0; b < bpt; ++b) cs += hist[b0 + b];
      unsigned v = cs;
      int lane = tid & 63;
#pragma unroll
      for (int st = 1; st < 64; st <<= 1) {
        unsigned tv = __shfl_down(v, st, 64);
        if (lane + st < 64) v += tv;
      }
      int w2 = tid >> 6;
      if (lane == 0) wtot[w2] = v;
      __syncthreads();
      unsigned above = 0;
      for (int ww = w2 + 1; ww < BLOCK / 64; ++ww) above += wtot[ww];
      unsigned S_incl = v + above;
      unsigned S_excl = S_incl - cs;
      if (S_excl < (unsigned)k && (unsigned)k <= S_incl) {  // unique winner
        int kk2 = k - (int)S_excl;
        int d = b0 + bpt - 1;
        for (; d > b0; --d) {
          int cb = (int)hist[d];
          if (kk2 <= cb) break;
          kk2 -= cb;
        }
        s_seld = (unsigned)d;
        s_selk = (unsigned)kk2;
        s_selc = hist[d];
      }
      __syncthreads();
      prefix |= s_seld << shift;
      pmask |= bmask << shift;
      k = (int)s_selk;
      unsigned selc = s_selc;
      if (lev == 2) {
        selkey = prefix;
        done = true;
      } else if (selc <= (unsigned)CAP) {
#pragma unroll
        for (int t = 0; t < 5; ++t)
          if (hv[t]) {
            unsigned kk[4] = {f2key(f[t].x), f2key(f[t].y), f2key(f[t].z), f2key(f[t].w)};
#pragma unroll
            for (int e = 0; e < 4; ++e)
              if ((kk[e] & pmask) == prefix) {
                unsigned q = atomicAdd(&bufcnt, 1u);
                if (q < CAP) buf[q] = kk[e];
              }
          }
        if (havet) {
          unsigned tk = f2key(tailv);
          if ((tk & pmask) == prefix) {
            unsigned q = atomicAdd(&bufcnt, 1u);
            if (q < CAP) buf[q] = tk;
          }
        }
        __syncthreads();
        int bc2 = (int)bufcnt;
        if (bc2 > CAP) bc2 = CAP;
        unsigned mk = (tid < bc2) ? buf[tid] : 0u;
        int g = 0, e2 = 0;
        for (int j = 0; j < bc2; ++j) {
          unsigned bk = buf[j];
          g += (bk > mk);
          e2 += (bk == mk);
        }
        if (tid < bc2 && g < k && k <= g + e2) s_key = mk;
        __syncthreads();
        selkey = s_key;
        done = true;
      }
    }
  }

  // ---- epilogue: branch select + rank loss ----
  if (tid == 0) {
    float x16 = key2f(selkey);
    float thres = sigm(fmaxf(x16, 0.0f));  // == max(sigmoid(x16), 0.5)
    unsigned gb = gtbits;
    float x1, x2;
    if (gb) {
      int first = __ffs((int)gb) - 1;
      x1 = sigm(key2f(lmaxk[first]));
      float ng = 0.0f;  // max over non-gt labels of sigmoid(x[b, l]), floor 0
      for (int l = 0; l < LBL; ++l)
        if (!((gb >> l) & 1)) ng = fmaxf(ng, sigm(smL[l]));
      x2 = fmaxf(ng, thres);
    } else {
      unsigned um = 0;
      for (int l = 0; l < LBL; ++l) um = um > lmaxk[l] ? um : lmaxk[l];
      x1 = thres;
      x2 = sigm(key2f(um));  // max over whitelist union
    }
    float dd = x2 - x1 + A1;
    float sg = 1.0f / (1.0f + __expf(-A3 * dd));
    rout[row] = (dd > 0.0f) ? A2 * sg : sg;
  }
}

__global__ __launch_bounds__(256) void reduce_kernel(const float* __restrict__ rin,
                                                     float* __restrict__ out, int B) {
  __shared__ float smr[256];
  float acc = 0.0f;
  for (int i = threadIdx.x; i < B; i += 256) acc += rin[i];
  smr[threadIdx.x] = acc;
  __syncthreads();
  for (int st = 128; st > 0; st >>= 1) {
    if (threadIdx.x < st) smr[threadIdx.x] += smr[threadIdx.x + st];
    __syncthreads();
  }
  if (threadIdx.x == 0) out[0] = smr[0];
}

extern "C" void kernel_launch(void* const* d_in, const int* in_sizes, int n_in,
                              void* d_out, int out_size, void* d_ws, size_t ws_size,
                              hipStream_t stream) {
  const float* x = (const float*)d_in[0];
  const float* y = (const float*)d_in[1];
  // d_in[2] (y_neg) is dead code w.r.t. the output.
  const unsigned char* wl = (const unsigned char*)d_in[3];

  int C = in_sizes[3] / LBL;
  int B = in_sizes[0] / C;
  int total = LBL * C;
  int* ws = (int*)d_ws;

  hipMemsetAsync(d_ws, 0, TBL0 * 4, stream);                       // flags
  hipMemsetAsync(ws + TBL0, 0xFF, (size_t)4 * TBLW * 4, stream);   // tables
  int nbs = (total + 255) / 256;
  hipLaunchKernelGGL(detect_kernel, dim3(nbs), dim3(256), 0, stream, wl, total, ws);
  int nbc = (C + 255) / 256;
  hipLaunchKernelGGL(build_lmap, dim3(nbc), dim3(256), 0, stream, wl, C, ws);

  hipLaunchKernelGGL(rank_kernel, dim3(B), dim3(BLOCK), 0, stream, x, y, ws,
                     (float*)(ws + WS_ROUT), C);
  hipLaunchKernelGGL(reduce_kernel, dim3(1), dim3(256), 0, stream,
                     (const float*)(ws + WS_ROUT), (float*)d_out, B);
}